// Round 13
// baseline (151.056 us; speedup 1.0000x reference)
//
#include <hip/hip_runtime.h>

// CrumbReconstructor R16: codebook streamed through SGPRs (inline-asm s_load,
// double-buffered 4-row chunks), ZERO LDS in the hot loop. The DS pipe —
// the serializing rail in every round R3-R15 — is simply not used.
//
// Why this beats R4's failed scalar attempt: R4's HIP-level uniform loads let
// the COMPILER place the lgkmcnt(0) (unordered SMEM => wait-all), and it
// drained the just-issued prefetch every chunk. Here the s_loads are inline
// asm (compiler inserts NO waits for them); our explicit s_waitcnt lgkmcnt(0)
// sits BEFORE the next buffer's issue, so each drain covers only loads issued
// a full ~368cy compute phase earlier -> latency fully hidden. sched_barrier
// (0) after each waitcnt per rule #18 (compiler hoists register-only FP ops
// past asm waitcnt otherwise).
//
// Rails: VALU = 3.06 waves/SIMD x 64 chunks x ~368cy = ~30us. SMEM traffic
// trivial (80B/chunk, L1-resident). No staging, no __syncthreads, no DS.
//
// Exactness (absmax must stay 0.0): DIST chain verbatim R13 (mul, 7x fmaf,
// fmaf(dot,-2,knorm), + rn); rn values from d_ws computed by norm_kernel
// with the IDENTICAL op tree; scan order 0..255 ascending; group-4 fmin
// tree (order-independent values, all finite); strict < keeps FIRST group;
// resolve recomputes from global mem with the same tree, first d == best.
// ws_size < 1KB falls back to the R13 kernel (passed, 72us).

#define LBLK 8          // memblock length
#define NROW 256        // codebook rows
#define BLOCK 64        // 1 wave per block
#define TPK 4           // keys per thread
#define WIN 4           // rows per chunk / argmin group

typedef float f32x16 __attribute__((ext_vector_type(16)));
typedef float f32x4s __attribute__((ext_vector_type(4)));

// --- pre-kernel: row norms -> d_ws (exact op tree, 1 block x 256 thr) ---
__global__ void norm_kernel(const float* __restrict__ mem,
                            float* __restrict__ nrm)
{
    const int i = threadIdx.x;
    const float4* g = (const float4*)mem;
    float4 a = g[i * 2 + 0];
    float4 b = g[i * 2 + 1];
    float q0 = a.x * a.x, q1 = a.y * a.y, q2 = a.z * a.z, q3 = a.w * a.w;
    float q4 = b.x * b.x, q5 = b.y * b.y, q6 = b.z * b.z, q7 = b.w * b.w;
    nrm[i] = ((q0 + q1) + (q2 + q3)) + ((q4 + q5) + (q6 + q7));
}

// the exact reference distance chain (bit-identical everywhere)
#define DIST(T, E0, E1, E2, E3, E4, E5, E6, E7, RN, DST)                \
    {                                                                   \
        float dot = k[(T)][0] * (E0);                                   \
        dot = fmaf(k[(T)][1], (E1), dot);                               \
        dot = fmaf(k[(T)][2], (E2), dot);                               \
        dot = fmaf(k[(T)][3], (E3), dot);                               \
        dot = fmaf(k[(T)][4], (E4), dot);                               \
        dot = fmaf(k[(T)][5], (E5), dot);                               \
        dot = fmaf(k[(T)][6], (E6), dot);                               \
        dot = fmaf(k[(T)][7], (E7), dot);                               \
        (DST) = fmaf(dot, -2.0f, knorm[(T)]) + (RN);                    \
    }

// issue one 4-row chunk: 2x s_load_dwordx16 (rows) + s_load_dwordx4 (norms)
#define SISSUE(R0, R1, RNV, PR, PN)                                     \
    asm volatile("s_load_dwordx16 %0, %3, 0\n\t"                        \
                 "s_load_dwordx16 %1, %3, 64\n\t"                       \
                 "s_load_dwordx4  %2, %4, 0"                            \
                 : "=&s"(R0), "=&s"(R1), "=&s"(RNV)                     \
                 : "s"(PR), "s"(PN));

// score one chunk (4 rows) for all TPK keys; group-4 argmin
#define COMPW(R0, R1, RNV, R)                                           \
    _Pragma("unroll")                                                   \
    for (int t = 0; t < TPK; ++t) {                                     \
        float d0, d1, d2, d3;                                           \
        DIST(t, (R0)[0], (R0)[1], (R0)[2], (R0)[3],                     \
                (R0)[4], (R0)[5], (R0)[6], (R0)[7],  (RNV)[0], d0);     \
        DIST(t, (R0)[8], (R0)[9], (R0)[10], (R0)[11],                   \
                (R0)[12], (R0)[13], (R0)[14], (R0)[15], (RNV)[1], d1);  \
        DIST(t, (R1)[0], (R1)[1], (R1)[2], (R1)[3],                     \
                (R1)[4], (R1)[5], (R1)[6], (R1)[7],  (RNV)[2], d2);     \
        DIST(t, (R1)[8], (R1)[9], (R1)[10], (R1)[11],                   \
                (R1)[12], (R1)[13], (R1)[14], (R1)[15], (RNV)[3], d3);  \
        float gm = fminf(fminf(d0, d1), fminf(d2, d3));                 \
        if (gm < best[t]) { best[t] = gm; gbs[t] = (R); }               \
    }

__global__ __launch_bounds__(BLOCK, 3) void crumb_kernel(
    const float* __restrict__ x,
    const float* __restrict__ mem,
    const float* __restrict__ nrm,
    float* __restrict__ out,
    int nblocks)
{
    const int lane = threadIdx.x;
    const long base = (long)blockIdx.x * (BLOCK * TPK) + lane;

    // --- load 4 keys per thread (coalesced per wave) ---
    float k[TPK][LBLK];
    float knorm[TPK];
    #pragma unroll
    for (int t = 0; t < TPK; ++t) {
        long b0 = base + (long)t * 64;
        long kbt = (b0 < (long)nblocks) ? b0 : 0;
        const float4* g = (const float4*)(x + kbt * LBLK);
        float4 a = g[0], b = g[1];
        k[t][0] = a.x; k[t][1] = a.y; k[t][2] = a.z; k[t][3] = a.w;
        k[t][4] = b.x; k[t][5] = b.y; k[t][6] = b.z; k[t][7] = b.w;
        float q0 = a.x * a.x, q1 = a.y * a.y, q2 = a.z * a.z, q3 = a.w * a.w;
        float q4 = b.x * b.x, q5 = b.y * b.y, q6 = b.z * b.z, q7 = b.w * b.w;
        knorm[t] = ((q0 + q1) + (q2 + q3)) + ((q4 + q5) + (q6 + q7));
    }

    float best[TPK];
    int   gbs[TPK];
    #pragma unroll
    for (int t = 0; t < TPK; ++t) { best[t] = 3.4e38f; gbs[t] = 0; }

    // --- SGPR double-buffered scan: 2 chunks (8 rows) per iteration ---
    f32x16 ra0, ra1; f32x4s rna;    // buffer A
    f32x16 rb0, rb1; f32x4s rnb;    // buffer B

    SISSUE(ra0, ra1, rna, mem, nrm);            // prolog: chunk 0 into A

    #pragma unroll 1
    for (int r = 0; r < NROW; r += 2 * WIN) {
        // A ready (only A's loads outstanding at this point)
        asm volatile("s_waitcnt lgkmcnt(0)" ::: "memory");
        __builtin_amdgcn_sched_barrier(0);
        {   // issue B = rows r+4 (in-flight across compute A)
            const float* pr = mem + (r + WIN) * LBLK;
            const float* pn = nrm + (r + WIN);
            SISSUE(rb0, rb1, rnb, pr, pn);
        }
        COMPW(ra0, ra1, rna, r);                // ~368cy covers B's latency
        __builtin_amdgcn_sched_barrier(0);

        // B ready (only B's loads outstanding)
        asm volatile("s_waitcnt lgkmcnt(0)" ::: "memory");
        __builtin_amdgcn_sched_barrier(0);
        {   // issue A' = rows (r+8) & 255 (wraps on last iter; values unused)
            const int rn2 = (r + 2 * WIN) & (NROW - 1);
            const float* pr = mem + rn2 * LBLK;
            const float* pn = nrm + rn2;
            SISSUE(ra0, ra1, rna, pr, pn);
        }
        COMPW(rb0, rb1, rnb, r + WIN);
        __builtin_amdgcn_sched_barrier(0);
    }
    asm volatile("s_waitcnt lgkmcnt(0)" ::: "memory");  // drain tail issue

    // --- resolve + store: recompute winning group from GLOBAL (L1-hot),
    //     take first d == best (lowest index), write its row (R13-verbatim) ---
    #pragma unroll
    for (int t = 0; t < TPK; ++t) {
        long b0 = base + (long)t * 64;
        if (b0 < (long)nblocks) {
            const int gb = gbs[t];
            float4 wa = ((const float4*)(mem + (long)gb * LBLK))[0];
            float4 wb = ((const float4*)(mem + (long)gb * LBLK))[1];
            bool found = false;
            #pragma unroll
            for (int j = 0; j < WIN; ++j) {
                const float4* g = (const float4*)(mem + (long)(gb + j) * LBLK);
                float4 a = g[0], b = g[1];
                float q0 = a.x * a.x, q1 = a.y * a.y, q2 = a.z * a.z, q3 = a.w * a.w;
                float q4 = b.x * b.x, q5 = b.y * b.y, q6 = b.z * b.z, q7 = b.w * b.w;
                float nn = ((q0 + q1) + (q2 + q3)) + ((q4 + q5) + (q6 + q7));
                float d;
                DIST(t, a.x, a.y, a.z, a.w, b.x, b.y, b.z, b.w, nn, d);
                bool hit = (d == best[t]) && !found;
                if (hit) { wa = a; wb = b; }
                found = found || (d == best[t]);
            }
            float4* o = (float4*)(out + b0 * LBLK);
            o[0] = wa;
            o[1] = wb;
        }
    }
}

// --- fallback (ws too small): R13 kernel verbatim (passed, 72us) ---
__global__ __launch_bounds__(BLOCK, 3) void crumb_kernel_lds(
    const float* __restrict__ x,
    const float* __restrict__ mem,
    float* __restrict__ out,
    int nblocks)
{
    __shared__ float s_mem[NROW * LBLK];
    __shared__ __align__(16) float s_norm[NROW];

    const int lane = threadIdx.x;
    {
        const float4* g = (const float4*)mem;
        #pragma unroll
        for (int c = 0; c < 4; ++c) {
            const int rr = c * 64 + lane;
            float4 a = g[rr * 2 + 0];
            float4 b = g[rr * 2 + 1];
            ((float4*)s_mem)[rr * 2 + 0] = a;
            ((float4*)s_mem)[rr * 2 + 1] = b;
            float q0 = a.x * a.x, q1 = a.y * a.y, q2 = a.z * a.z, q3 = a.w * a.w;
            float q4 = b.x * b.x, q5 = b.y * b.y, q6 = b.z * b.z, q7 = b.w * b.w;
            s_norm[rr] = ((q0 + q1) + (q2 + q3)) + ((q4 + q5) + (q6 + q7));
        }
    }
    __syncthreads();

    const long base = (long)blockIdx.x * (BLOCK * TPK) + lane;
    float k[TPK][LBLK];
    float knorm[TPK];
    #pragma unroll
    for (int t = 0; t < TPK; ++t) {
        long b0 = base + (long)t * 64;
        long kbt = (b0 < (long)nblocks) ? b0 : 0;
        const float4* g = (const float4*)(x + kbt * LBLK);
        float4 a = g[0], b = g[1];
        k[t][0] = a.x; k[t][1] = a.y; k[t][2] = a.z; k[t][3] = a.w;
        k[t][4] = b.x; k[t][5] = b.y; k[t][6] = b.z; k[t][7] = b.w;
        float q0 = a.x * a.x, q1 = a.y * a.y, q2 = a.z * a.z, q3 = a.w * a.w;
        float q4 = b.x * b.x, q5 = b.y * b.y, q6 = b.z * b.z, q7 = b.w * b.w;
        knorm[t] = ((q0 + q1) + (q2 + q3)) + ((q4 + q5) + (q6 + q7));
    }

    float best[TPK];
    int   gbs[TPK];
    #pragma unroll
    for (int t = 0; t < TPK; ++t) { best[t] = 3.4e38f; gbs[t] = 0; }

    const float4* sm4 = (const float4*)s_mem;
    #pragma unroll 1
    for (int r = 0; r < NROW; r += WIN) {
        float4 A0 = sm4[(r + 0) * 2 + 0], B0 = sm4[(r + 0) * 2 + 1];
        float4 A1 = sm4[(r + 1) * 2 + 0], B1 = sm4[(r + 1) * 2 + 1];
        float4 A2 = sm4[(r + 2) * 2 + 0], B2 = sm4[(r + 2) * 2 + 1];
        float4 A3 = sm4[(r + 3) * 2 + 0], B3 = sm4[(r + 3) * 2 + 1];
        float4 N  = *(const float4*)&s_norm[r];
        #pragma unroll
        for (int t = 0; t < TPK; ++t) {
            float d0, d1, d2, d3;
            DIST(t, A0.x, A0.y, A0.z, A0.w, B0.x, B0.y, B0.z, B0.w, N.x, d0);
            DIST(t, A1.x, A1.y, A1.z, A1.w, B1.x, B1.y, B1.z, B1.w, N.y, d1);
            DIST(t, A2.x, A2.y, A2.z, A2.w, B2.x, B2.y, B2.z, B2.w, N.z, d2);
            DIST(t, A3.x, A3.y, A3.z, A3.w, B3.x, B3.y, B3.z, B3.w, N.w, d3);
            float gm = fminf(fminf(d0, d1), fminf(d2, d3));
            if (gm < best[t]) { best[t] = gm; gbs[t] = r; }
        }
    }

    #pragma unroll
    for (int t = 0; t < TPK; ++t) {
        long b0 = base + (long)t * 64;
        if (b0 < (long)nblocks) {
            const int gb = gbs[t];
            float4 wa = ((const float4*)(mem + (long)gb * LBLK))[0];
            float4 wb = ((const float4*)(mem + (long)gb * LBLK))[1];
            bool found = false;
            #pragma unroll
            for (int j = 0; j < WIN; ++j) {
                const float4* g = (const float4*)(mem + (long)(gb + j) * LBLK);
                float4 a = g[0], b = g[1];
                float q0 = a.x * a.x, q1 = a.y * a.y, q2 = a.z * a.z, q3 = a.w * a.w;
                float q4 = b.x * b.x, q5 = b.y * b.y, q6 = b.z * b.z, q7 = b.w * b.w;
                float nn = ((q0 + q1) + (q2 + q3)) + ((q4 + q5) + (q6 + q7));
                float d;
                DIST(t, a.x, a.y, a.z, a.w, b.x, b.y, b.z, b.w, nn, d);
                bool hit = (d == best[t]) && !found;
                if (hit) { wa = a; wb = b; }
                found = found || (d == best[t]);
            }
            float4* o = (float4*)(out + b0 * LBLK);
            o[0] = wa;
            o[1] = wb;
        }
    }
}

extern "C" void kernel_launch(void* const* d_in, const int* in_sizes, int n_in,
                              void* d_out, int out_size, void* d_ws, size_t ws_size,
                              hipStream_t stream) {
    const float* x   = (const float*)d_in[0];
    const float* mem = (const float*)d_in[1];
    float* out = (float*)d_out;

    int n = in_sizes[0];            // total x elements
    int nblocks = n / LBLK;         // key-blocks (802816 for std shape)
    int grid = (nblocks + BLOCK * TPK - 1) / (BLOCK * TPK);   // 3136

    if (ws_size >= NROW * sizeof(float) && d_ws != nullptr) {
        float* nrm = (float*)d_ws;
        hipLaunchKernelGGL(norm_kernel, dim3(1), dim3(NROW), 0, stream, mem, nrm);
        hipLaunchKernelGGL(crumb_kernel, dim3(grid), dim3(BLOCK), 0, stream,
                           x, mem, nrm, out, nblocks);
    } else {
        hipLaunchKernelGGL(crumb_kernel_lds, dim3(grid), dim3(BLOCK), 0, stream,
                           x, mem, out, nblocks);
    }
}

// Round 14
// 122.994 us; speedup vs baseline: 1.2282x; 1.2282x over previous
//
#include <hip/hip_runtime.h>

// CrumbReconstructor R17: row-split across the block's two waves (the only
// untested structure that halves per-wave DS reads at CONSTANT wave count),
// built from R13's codegen-proven scan body.
//
// Map after 16 rounds: DS-broadcast ~70-72us, SMEM-stream 89, readlane 107;
// packing/pipelining neutral or worse. DS pipe cost is per-instruction
// (~12cy/ds_read_b128, per-CU shared): 24.5 waves/CU x 576 reads = 71us at
// TPK=2 (R12, measured 69.5). Row-split: each wave reads 128 rows -> 288
// reads -> DS/CU = 35us; VALU/SIMD = 38us; at 6.1 waves/SIMD (max-overlap
// regime, R12-proven) predict ~48-60us.
//
// R10 failed on CODEGEN (VGPR=40, k[] through AGPRs, spill) not structure.
// R13's body (same k[4][8], WIN=4 group-min, global resolve) compiled clean
// at VGPR 52 -> reused verbatim; only rbase and the merge tail differ.
// __launch_bounds__(128,8) pins VGPR<=64 so 24.5 waves/CU reside
// (LDS 11.25KB x 12.25 blocks = 138KB < 160KB).
//
// Exactness (absmax must stay 0.0):
//  - DIST chain verbatim (mul, 7x fmaf, fmaf(dot,-2,knorm), +rn);
//  - per-half scan keeps FIRST group attaining that half's min (strict <);
//  - cross-half merge on u64 = orderedbits(groupmin)<<32 | gbase: groups
//    before the true winner have strictly greater groupmin; equal-dist tie
//    picks smaller gbase (= lo half = earlier index). orderedbits is the
//    standard sign-fold total order (bijective, monotone over all floats);
//  - resolve recomputes the winning group's 4 distances from global with
//    the same op tree and takes the FIRST d == best -> reference argmin.

#define LBLK 8          // memblock length
#define NROW 256        // codebook rows
#define HROW 128        // rows per wave (half the row space)
#define BLOCK 128       // 2 waves per block
#define TPK 4           // keys per thread; block covers 256 keys
#define WIN 4           // rows per window / argmin group

__device__ __forceinline__ unsigned long long packdi(float d, int g) {
    unsigned int b  = __float_as_uint(d);
    unsigned int ob = (b >> 31) ? ~b : (b | 0x80000000u);   // total order
    return ((unsigned long long)ob << 32) | (unsigned int)g;
}

__global__ __launch_bounds__(BLOCK, 8) void crumb_kernel(
    const float* __restrict__ x,
    const float* __restrict__ mem,
    float* __restrict__ out,
    int nblocks)
{
    __shared__ float s_mem[NROW * LBLK];            // 8 KB, rows contiguous
    __shared__ __align__(16) float s_norm[NROW];    // 1 KB, b128 window reads
    __shared__ unsigned long long s_pub[NROW];      // 2 KB, cross-wave merge

    const int tid  = threadIdx.x;
    const int lane = tid & 63;
    const int wid  = tid >> 6;          // 0: rows 0..127, 1: rows 128..255

    // --- stage codebook: 2 rows per thread, coalesced ---
    {
        const float4* g = (const float4*)mem;
        #pragma unroll
        for (int c = 0; c < 2; ++c) {
            const int rr = c * BLOCK + tid;
            float4 a = g[rr * 2 + 0];
            float4 b = g[rr * 2 + 1];
            ((float4*)s_mem)[rr * 2 + 0] = a;
            ((float4*)s_mem)[rr * 2 + 1] = b;
            float q0 = a.x * a.x, q1 = a.y * a.y, q2 = a.z * a.z, q3 = a.w * a.w;
            float q4 = b.x * b.x, q5 = b.y * b.y, q6 = b.z * b.z, q7 = b.w * b.w;
            s_norm[rr] = ((q0 + q1) + (q2 + q3)) + ((q4 + q5) + (q6 + q7));
        }
    }
    __syncthreads();

    // --- load the block's 256 keys (both waves load the same keys) ---
    float k[TPK][LBLK];
    float knorm[TPK];

    #pragma unroll
    for (int t = 0; t < TPK; ++t) {
        long b0 = (long)blockIdx.x * 256 + t * 64 + lane;
        long kbt = (b0 < (long)nblocks) ? b0 : 0;
        const float4* g = (const float4*)(x + kbt * LBLK);
        float4 a = g[0], b = g[1];
        k[t][0] = a.x; k[t][1] = a.y; k[t][2] = a.z; k[t][3] = a.w;
        k[t][4] = b.x; k[t][5] = b.y; k[t][6] = b.z; k[t][7] = b.w;
        float q0 = a.x * a.x, q1 = a.y * a.y, q2 = a.z * a.z, q3 = a.w * a.w;
        float q4 = b.x * b.x, q5 = b.y * b.y, q6 = b.z * b.z, q7 = b.w * b.w;
        knorm[t] = ((q0 + q1) + (q2 + q3)) + ((q4 + q5) + (q6 + q7));
    }

    float best[TPK];
    int   gbs[TPK];
    const int rbase = wid * HROW;
    #pragma unroll
    for (int t = 0; t < TPK; ++t) { best[t] = 3.4e38f; gbs[t] = rbase; }

    const float4* sm4 = (const float4*)s_mem;

    // the exact reference distance chain (bit-identical everywhere)
#define DIST(T, RA, RB, RN, DST)                                        \
    {                                                                   \
        float dot = k[(T)][0] * (RA).x;                                 \
        dot = fmaf(k[(T)][1], (RA).y, dot);                             \
        dot = fmaf(k[(T)][2], (RA).z, dot);                             \
        dot = fmaf(k[(T)][3], (RA).w, dot);                             \
        dot = fmaf(k[(T)][4], (RB).x, dot);                             \
        dot = fmaf(k[(T)][5], (RB).y, dot);                             \
        dot = fmaf(k[(T)][6], (RB).z, dot);                             \
        dot = fmaf(k[(T)][7], (RB).w, dot);                             \
        (DST) = fmaf(dot, -2.0f, knorm[(T)]) + (RN);                    \
    }

    // --- scan this wave's 128 rows: R13 body verbatim, 4-row windows ---
    #pragma unroll 1
    for (int w = 0; w < HROW; w += WIN) {
        const int r = rbase + w;
        float4 A0 = sm4[(r + 0) * 2 + 0], B0 = sm4[(r + 0) * 2 + 1];
        float4 A1 = sm4[(r + 1) * 2 + 0], B1 = sm4[(r + 1) * 2 + 1];
        float4 A2 = sm4[(r + 2) * 2 + 0], B2 = sm4[(r + 2) * 2 + 1];
        float4 A3 = sm4[(r + 3) * 2 + 0], B3 = sm4[(r + 3) * 2 + 1];
        float4 N  = *(const float4*)&s_norm[r];

        #pragma unroll
        for (int t = 0; t < TPK; ++t) {
            float d0, d1, d2, d3;
            DIST(t, A0, B0, N.x, d0);
            DIST(t, A1, B1, N.y, d1);
            DIST(t, A2, B2, N.z, d2);
            DIST(t, A3, B3, N.w, d3);
            // group min (order-independent value; all inputs finite)
            float gm = fminf(fminf(d0, d1), fminf(d2, d3));
            // strict < : FIRST group attaining this half's min wins
            if (gm < best[t]) { best[t] = gm; gbs[t] = r; }
        }
    }

    // --- publish for the OTHER wave's finalize set ---
    // wave0 finalizes t={0,1}  -> wave1 publishes its t0,t1 at [0..127]
    // wave1 finalizes t={2,3}  -> wave0 publishes its t2,t3 at [128..255]
    if (wid == 0) {
        s_pub[128 + lane] = packdi(best[2], gbs[2]);
        s_pub[192 + lane] = packdi(best[3], gbs[3]);
    } else {
        s_pub[0  + lane] = packdi(best[0], gbs[0]);
        s_pub[64 + lane] = packdi(best[1], gbs[1]);
    }
    __syncthreads();

    // --- finalize two keys per wave: u64-min merge, global resolve, store ---
#define FINALIZE(T)                                                     \
    {                                                                   \
        long b0 = (long)blockIdx.x * 256 + (T) * 64 + lane;             \
        if (b0 < (long)nblocks) {                                       \
            unsigned long long own = packdi(best[(T)], gbs[(T)]);       \
            unsigned long long oth = s_pub[(T) * 64 + lane];            \
            unsigned long long winv = own < oth ? own : oth;            \
            unsigned int ob = (unsigned int)(winv >> 32);               \
            unsigned int bb = (ob & 0x80000000u) ? (ob ^ 0x80000000u)   \
                                                 : ~ob;                 \
            float fb = __uint_as_float(bb);                             \
            int   gb = (int)(winv & 0xffffffffu);                       \
            float4 wa = ((const float4*)(mem + (long)gb * LBLK))[0];    \
            float4 wb = ((const float4*)(mem + (long)gb * LBLK))[1];    \
            bool found = false;                                         \
            _Pragma("unroll")                                           \
            for (int j = 0; j < WIN; ++j) {                             \
                const float4* g =                                       \
                    (const float4*)(mem + (long)(gb + j) * LBLK);       \
                float4 a = g[0], b = g[1];                              \
                float q0 = a.x * a.x, q1 = a.y * a.y;                   \
                float q2 = a.z * a.z, q3 = a.w * a.w;                   \
                float q4 = b.x * b.x, q5 = b.y * b.y;                   \
                float q6 = b.z * b.z, q7 = b.w * b.w;                   \
                float nn = ((q0 + q1) + (q2 + q3))                      \
                         + ((q4 + q5) + (q6 + q7));                     \
                float d;                                                \
                DIST((T), a, b, nn, d);                                 \
                bool hit = (d == fb) && !found;                         \
                if (hit) { wa = a; wb = b; }                            \
                found = found || (d == fb);                             \
            }                                                           \
            float4* o = (float4*)(out + b0 * LBLK);                     \
            o[0] = wa;                                                  \
            o[1] = wb;                                                  \
        }                                                               \
    }

    if (wid == 0) {
        FINALIZE(0);
        FINALIZE(1);
    } else {
        FINALIZE(2);
        FINALIZE(3);
    }
#undef FINALIZE
#undef DIST
}

extern "C" void kernel_launch(void* const* d_in, const int* in_sizes, int n_in,
                              void* d_out, int out_size, void* d_ws, size_t ws_size,
                              hipStream_t stream) {
    const float* x   = (const float*)d_in[0];
    const float* mem = (const float*)d_in[1];
    float* out = (float*)d_out;

    int n = in_sizes[0];            // total x elements
    int nblocks = n / LBLK;         // key-blocks (802816 for std shape)
    int grid = (nblocks + 255) / 256;   // 3136 for std shape

    hipLaunchKernelGGL(crumb_kernel, dim3(grid), dim3(BLOCK), 0, stream,
                       x, mem, out, nblocks);
}

// Round 16
// 120.328 us; speedup vs baseline: 1.2554x; 1.0222x over previous
//
#include <hip/hip_runtime.h>

// CrumbReconstructor R18b: resubmission of R18 (round 15 was an infra
// failure — container died twice, no kernel verdict).
//
// R17's row-split deepened to 4 waves (quarter-scan). Same total DS reads
// and VALU ops as R17; 4x finer per-wave bursts + 2x launched waves so the
// CU can TILE the DS and VALU phases across waves.
//
// R17 post-mortem (65.3us champion): measured ~= DS(35) + VALU(29) SUM ->
// phases still serialize at 2 coarse waves/block. R12-vs-R17 proved total-
// work cuts move the wall; overlap is the remaining ~2x. W=4 attacks only
// the overlap axis: per-wave burst 144 ds_reads / ~5.6Kcy VALU, 12544 waves
// (49/CU oversubscribed -> full residency in shifts).
//
// Merge: R17's u64 pack (orderedbits(dist)<<32 | gbase) min over 4 quarters.
// Exact: within-quarter strict < keeps FIRST group of that quarter's min;
// u64-min across quarters -> smallest distance, tie -> smallest gbase =
// earliest index. Resolve recomputes the winning group's 4 distances from
// global (L1-hot) with the identical op tree, takes first d == best.
// Publish buffer ALIASED onto s_mem (dead after scan, 8KB exactly, align16
// covers u64; barriers on both sides): LDS stays 9.25KB.
// Finalize uses compile-time T via 4-way branch (rule #20); wave wid==T
// finalizes keys T*64+lane using its own k[T] (all waves hold all keys).
//
// Exactness (absmax must stay 0.0): DIST chain verbatim R13/R17 (mul,
// 7x fmaf, fmaf(dot,-2,knorm), + rn); scan order within quarter ascending;
// group-4 fmin tree order-independent (all finite).

#define LBLK 8          // memblock length
#define NROW 256        // codebook rows
#define QROW 64         // rows per wave (quarter of the row space)
#define BLOCK 256       // 4 waves per block
#define TPK 4           // keys per thread; block covers 256 keys
#define WIN 4           // rows per window / argmin group

__device__ __forceinline__ unsigned long long packdi(float d, int g) {
    unsigned int b  = __float_as_uint(d);
    unsigned int ob = (b >> 31) ? ~b : (b | 0x80000000u);   // total order
    return ((unsigned long long)ob << 32) | (unsigned int)g;
}

__global__ __launch_bounds__(BLOCK, 4) void crumb_kernel(
    const float* __restrict__ x,
    const float* __restrict__ mem,
    float* __restrict__ out,
    int nblocks)
{
    __shared__ __align__(16) float s_mem[NROW * LBLK];   // 8 KB; publish alias
    __shared__ __align__(16) float s_norm[NROW];         // 1 KB

    const int tid  = threadIdx.x;
    const int lane = tid & 63;
    const int wid  = tid >> 6;          // wave w scans rows [w*64, w*64+64)

    // --- stage codebook: 1 row per thread, coalesced ---
    {
        const float4* g = (const float4*)mem;
        float4 a = g[tid * 2 + 0];
        float4 b = g[tid * 2 + 1];
        ((float4*)s_mem)[tid * 2 + 0] = a;
        ((float4*)s_mem)[tid * 2 + 1] = b;
        float q0 = a.x * a.x, q1 = a.y * a.y, q2 = a.z * a.z, q3 = a.w * a.w;
        float q4 = b.x * b.x, q5 = b.y * b.y, q6 = b.z * b.z, q7 = b.w * b.w;
        s_norm[tid] = ((q0 + q1) + (q2 + q3)) + ((q4 + q5) + (q6 + q7));
    }
    __syncthreads();

    // --- load the block's 256 keys (all 4 waves load the same keys) ---
    float k[TPK][LBLK];
    float knorm[TPK];

    #pragma unroll
    for (int t = 0; t < TPK; ++t) {
        long b0 = (long)blockIdx.x * 256 + t * 64 + lane;
        long kbt = (b0 < (long)nblocks) ? b0 : 0;
        const float4* g = (const float4*)(x + kbt * LBLK);
        float4 a = g[0], b = g[1];
        k[t][0] = a.x; k[t][1] = a.y; k[t][2] = a.z; k[t][3] = a.w;
        k[t][4] = b.x; k[t][5] = b.y; k[t][6] = b.z; k[t][7] = b.w;
        float q0 = a.x * a.x, q1 = a.y * a.y, q2 = a.z * a.z, q3 = a.w * a.w;
        float q4 = b.x * b.x, q5 = b.y * b.y, q6 = b.z * b.z, q7 = b.w * b.w;
        knorm[t] = ((q0 + q1) + (q2 + q3)) + ((q4 + q5) + (q6 + q7));
    }

    float best[TPK];
    int   gbs[TPK];
    const int rbase = wid * QROW;
    #pragma unroll
    for (int t = 0; t < TPK; ++t) { best[t] = 3.4e38f; gbs[t] = rbase; }

    const float4* sm4 = (const float4*)s_mem;

    // the exact reference distance chain (bit-identical everywhere)
#define DIST(T, RA, RB, RN, DST)                                        \
    {                                                                   \
        float dot = k[(T)][0] * (RA).x;                                 \
        dot = fmaf(k[(T)][1], (RA).y, dot);                             \
        dot = fmaf(k[(T)][2], (RA).z, dot);                             \
        dot = fmaf(k[(T)][3], (RA).w, dot);                             \
        dot = fmaf(k[(T)][4], (RB).x, dot);                             \
        dot = fmaf(k[(T)][5], (RB).y, dot);                             \
        dot = fmaf(k[(T)][6], (RB).z, dot);                             \
        dot = fmaf(k[(T)][7], (RB).w, dot);                             \
        (DST) = fmaf(dot, -2.0f, knorm[(T)]) + (RN);                    \
    }

    // --- scan this wave's 64 rows: 16 windows of 4 (R13/R17-proven body) ---
    #pragma unroll 1
    for (int w = 0; w < QROW; w += WIN) {
        const int r = rbase + w;
        float4 A0 = sm4[(r + 0) * 2 + 0], B0 = sm4[(r + 0) * 2 + 1];
        float4 A1 = sm4[(r + 1) * 2 + 0], B1 = sm4[(r + 1) * 2 + 1];
        float4 A2 = sm4[(r + 2) * 2 + 0], B2 = sm4[(r + 2) * 2 + 1];
        float4 A3 = sm4[(r + 3) * 2 + 0], B3 = sm4[(r + 3) * 2 + 1];
        float4 N  = *(const float4*)&s_norm[r];

        #pragma unroll
        for (int t = 0; t < TPK; ++t) {
            float d0, d1, d2, d3;
            DIST(t, A0, B0, N.x, d0);
            DIST(t, A1, B1, N.y, d1);
            DIST(t, A2, B2, N.z, d2);
            DIST(t, A3, B3, N.w, d3);
            // group min (order-independent value; all inputs finite)
            float gm = fminf(fminf(d0, d1), fminf(d2, d3));
            // strict < : FIRST group attaining this quarter's min wins
            if (gm < best[t]) { best[t] = gm; gbs[t] = r; }
        }
    }

    // --- publish: alias s_pub onto s_mem (dead after scan) ---
    __syncthreads();                 // all scan reads of s_mem complete
    unsigned long long* s_pub = (unsigned long long*)s_mem;   // [4][256]
    #pragma unroll
    for (int t = 0; t < TPK; ++t)
        s_pub[wid * 256 + t * 64 + lane] = packdi(best[t], gbs[t]);
    __syncthreads();

    // --- finalize: wave w owns keys t == w; u64-min over 4 quarters,
    //     resolve from global (L1-hot), store ---
#define FINALIZE(T)                                                     \
    {                                                                   \
        long b0 = (long)blockIdx.x * 256 + (T) * 64 + lane;             \
        if (b0 < (long)nblocks) {                                       \
            const int key = (T) * 64 + lane;                            \
            unsigned long long m0 = s_pub[0 * 256 + key];               \
            unsigned long long m1 = s_pub[1 * 256 + key];               \
            unsigned long long m2 = s_pub[2 * 256 + key];               \
            unsigned long long m3 = s_pub[3 * 256 + key];               \
            unsigned long long winv = m0 < m1 ? m0 : m1;                \
            winv = winv < m2 ? winv : m2;                               \
            winv = winv < m3 ? winv : m3;                               \
            unsigned int ob = (unsigned int)(winv >> 32);               \
            unsigned int bb = (ob & 0x80000000u) ? (ob ^ 0x80000000u)   \
                                                 : ~ob;                 \
            float fb = __uint_as_float(bb);                             \
            int   gb = (int)(winv & 0xffffffffu);                       \
            float4 wa = ((const float4*)(mem + (long)gb * LBLK))[0];    \
            float4 wb = ((const float4*)(mem + (long)gb * LBLK))[1];    \
            bool found = false;                                         \
            _Pragma("unroll")                                           \
            for (int j = 0; j < WIN; ++j) {                             \
                const float4* g =                                       \
                    (const float4*)(mem + (long)(gb + j) * LBLK);       \
                float4 a = g[0], b = g[1];                              \
                float q0 = a.x * a.x, q1 = a.y * a.y;                   \
                float q2 = a.z * a.z, q3 = a.w * a.w;                   \
                float q4 = b.x * b.x, q5 = b.y * b.y;                   \
                float q6 = b.z * b.z, q7 = b.w * b.w;                   \
                float nn = ((q0 + q1) + (q2 + q3))                      \
                         + ((q4 + q5) + (q6 + q7));                     \
                float d;                                                \
                DIST((T), a, b, nn, d);                                 \
                bool hit = (d == fb) && !found;                         \
                if (hit) { wa = a; wb = b; }                            \
                found = found || (d == fb);                             \
            }                                                           \
            float4* o = (float4*)(out + b0 * LBLK);                     \
            o[0] = wa;                                                  \
            o[1] = wb;                                                  \
        }                                                               \
    }

    if      (wid == 0) FINALIZE(0)
    else if (wid == 1) FINALIZE(1)
    else if (wid == 2) FINALIZE(2)
    else               FINALIZE(3)
#undef FINALIZE
#undef DIST
}

extern "C" void kernel_launch(void* const* d_in, const int* in_sizes, int n_in,
                              void* d_out, int out_size, void* d_ws, size_t ws_size,
                              hipStream_t stream) {
    const float* x   = (const float*)d_in[0];
    const float* mem = (const float*)d_in[1];
    float* out = (float*)d_out;

    int n = in_sizes[0];            // total x elements
    int nblocks = n / LBLK;         // key-blocks (802816 for std shape)
    int grid = (nblocks + 255) / 256;   // 3136 for std shape

    hipLaunchKernelGGL(crumb_kernel, dim3(grid), dim3(BLOCK), 0, stream,
                       x, mem, out, nblocks);
}